// Round 6
// baseline (6603.332 us; speedup 1.0000x reference)
//
#include <hip/hip_runtime.h>

// LSTM: H=1024, B=1024, S=128 (T=127 steps), E=6, V=3, C=10.
// All float tensors FP32; x int32; output FP32 (1024 x 10).
// Multi-launch design (kernel boundaries = bulletproof inter-step sync,
// replacing R5's hand-rolled grid barrier, the prime suspect for R5's
// finite-wrong result): 3 prep launches + 127 step launches + logits.
// Recurrent GEMM in bf16 MFMA (error analysis: contractive dynamics, steady
// state h error ~0.005 << 0.0615 threshold). Workspace ~16.1 MB.
constexpr int kH = 1024;
constexpr int kB = 1024;
constexpr int kS = 128;
constexpr int kT = 127;
constexpr int kE = 6;
constexpr int kV = 3;
constexpr int kC = 10;

typedef short s16x8 __attribute__((ext_vector_type(8)));
typedef short s16x4 __attribute__((ext_vector_type(4)));
typedef float f32x4 __attribute__((ext_vector_type(4)));
typedef unsigned short u16;

__device__ __forceinline__ float b2f(u16 u) {
    return __uint_as_float(((unsigned)u) << 16);
}
__device__ __forceinline__ u16 f2b(float f) {
    unsigned u = __float_as_uint(f);
    return (u16)((u + 0x7FFFu + ((u >> 16) & 1u)) >> 16);   // RNE
}
__device__ __forceinline__ float sigmoid_fast(float x) {
    return 1.0f / (1.0f + __expf(-x));
}
__device__ __forceinline__ float tanh_fast(float x) {
    return 2.0f / (1.0f + __expf(-2.0f * x)) - 1.0f;
}
__device__ __forceinline__ float clamp30(float x) {   // saturation-invisible
    return fminf(fmaxf(x, -30.0f), 30.0f);
}

// ---------------------------------------------------------------------------
// Prep 1: recurrent weights fp32 -> bf16. 2048 blocks x 256 thr x 8 elems.
// wbf flat layout: [g][row][k], g in {g,i,f,o}.
// ---------------------------------------------------------------------------
__global__ __launch_bounds__(256) void prep_weights(
    const float* __restrict__ Wgh, const float* __restrict__ Wih,
    const float* __restrict__ Wfh, const float* __restrict__ Woh,
    u16* __restrict__ wbf)
{
    size_t i = ((size_t)blockIdx.x * 256 + threadIdx.x) * 8;   // 0 .. 4M-8
    int g = (int)(i >> 20);
    size_t off = i & 0xFFFFFu;
    const float* src = (g == 0) ? Wgh : (g == 1) ? Wih : (g == 2) ? Wfh : Woh;
    f32x4 v0 = *(const f32x4*)(src + off);
    f32x4 v1 = *(const f32x4*)(src + off + 4);
    s16x8 o;
#pragma unroll
    for (int j = 0; j < 4; ++j) o[j] = (short)f2b(v0[j]);
#pragma unroll
    for (int j = 0; j < 4; ++j) o[4 + j] = (short)f2b(v1[j]);
    *(s16x8*)(wbf + i) = o;
}

// ---------------------------------------------------------------------------
// Prep 2: transpose h0 (H,B) fp32 -> hA (B,H) bf16; c0 (H,B) -> cT (B,H) fp32.
// ---------------------------------------------------------------------------
__global__ __launch_bounds__(1024) void prep_hc(
    const float* __restrict__ h0, const float* __restrict__ c0,
    u16* __restrict__ hA, float* __restrict__ cT)
{
    __shared__ float th[32][33];
    __shared__ float tc[32][33];
    int b = blockIdx.x * 32 + threadIdx.x;
    int h = blockIdx.y * 32 + threadIdx.y;
    th[threadIdx.y][threadIdx.x] = h0[(size_t)h * kB + b];
    tc[threadIdx.y][threadIdx.x] = c0[(size_t)h * kB + b];
    __syncthreads();
    int ob = blockIdx.x * 32 + threadIdx.y;
    int oh = blockIdx.y * 32 + threadIdx.x;
    hA[(size_t)ob * kH + oh] = f2b(th[threadIdx.x][threadIdx.y]);
    cT[(size_t)ob * kH + oh] = tc[threadIdx.x][threadIdx.y];
}

// ---------------------------------------------------------------------------
// Prep 3: Q[g][h][v] = b_g[h] + sum_e W_gx[h,e]*emb[v,e]  (fp32, stride 4)
// ---------------------------------------------------------------------------
__global__ __launch_bounds__(256) void prep_q(
    const float* __restrict__ Wgx, const float* __restrict__ Wix,
    const float* __restrict__ Wfx, const float* __restrict__ Wox,
    const float* __restrict__ bg,  const float* __restrict__ bi,
    const float* __restrict__ bf_, const float* __restrict__ bo,
    const float* __restrict__ emb, float* __restrict__ Q)
{
    int tid = blockIdx.x * blockDim.x + threadIdx.x;
    if (tid >= 4 * kH) return;
    int g = tid >> 10;
    int h = tid & (kH - 1);
    const float* Wx = (g == 0) ? Wgx : (g == 1) ? Wix : (g == 2) ? Wfx : Wox;
    const float* bb = (g == 0) ? bg  : (g == 1) ? bi  : (g == 2) ? bf_ : bo;
    float w[kE];
#pragma unroll
    for (int e = 0; e < kE; ++e) w[e] = Wx[h * kE + e];
#pragma unroll
    for (int v = 0; v < kV; ++v) {
        float s = bb[h];
#pragma unroll
        for (int e = 0; e < kE; ++e) s += w[e] * emb[v * kE + e];
        Q[tid * 4 + v] = s;
    }
    Q[tid * 4 + 3] = 0.0f;
}

// ---------------------------------------------------------------------------
// One LSTM timestep: fused 4-gate GEMM (NT, bf16 MFMA 16x16x32) + pointwise.
// Grid (B/128=8, H/32=32), block 256 (4 waves). Wave w: rows [by*32,+32),
// cols [bx*128+32w,+32). h (B,H) bf16 K-contig; c (B,H) fp32 in-place.
// ---------------------------------------------------------------------------
__global__ __launch_bounds__(256) void lstm_step(
    const short* __restrict__ wbf, const float* __restrict__ Q,
    const int* __restrict__ x, int t,
    const short* __restrict__ hin, u16* __restrict__ hout,
    float* __restrict__ cT)
{
    const int lane = threadIdx.x & 63;
    const int wave = threadIdx.x >> 6;
    const int lm   = lane & 15;
    const int quad = lane >> 4;
    const int r0 = blockIdx.y * 32;
    const int c0 = blockIdx.x * 128 + wave * 32;

    f32x4 acc[4][2][2];
    const f32x4 zero = {0.f, 0.f, 0.f, 0.f};
#pragma unroll
    for (int g = 0; g < 4; ++g)
#pragma unroll
        for (int m = 0; m < 2; ++m)
#pragma unroll
            for (int n = 0; n < 2; ++n) acc[g][m][n] = zero;

    const int koff = quad * 8;   // A/B frag: elem j -> k = quad*8+j (m120)
    const short* hrow0 = hin + (size_t)(c0 + lm) * kH + koff;
    const short* hrow1 = hin + (size_t)(c0 + 16 + lm) * kH + koff;
    const short* arow[4][2];
#pragma unroll
    for (int g = 0; g < 4; ++g) {
        const short* wg = wbf + (size_t)g * kH * kH;
        arow[g][0] = wg + (size_t)(r0 + lm) * kH + koff;
        arow[g][1] = wg + (size_t)(r0 + 16 + lm) * kH + koff;
    }

    for (int k0 = 0; k0 < kH; k0 += 32) {
        s16x8 b0 = *(const s16x8*)(hrow0 + k0);
        s16x8 b1 = *(const s16x8*)(hrow1 + k0);
#pragma unroll
        for (int g = 0; g < 4; ++g) {
            s16x8 a0 = *(const s16x8*)(arow[g][0] + k0);
            s16x8 a1 = *(const s16x8*)(arow[g][1] + k0);
            acc[g][0][0] = __builtin_amdgcn_mfma_f32_16x16x32_bf16(a0, b0, acc[g][0][0], 0, 0, 0);
            acc[g][0][1] = __builtin_amdgcn_mfma_f32_16x16x32_bf16(a0, b1, acc[g][0][1], 0, 0, 0);
            acc[g][1][0] = __builtin_amdgcn_mfma_f32_16x16x32_bf16(a1, b0, acc[g][1][0], 0, 0, 0);
            acc[g][1][1] = __builtin_amdgcn_mfma_f32_16x16x32_bf16(a1, b1, acc[g][1][1], 0, 0, 0);
        }
    }

    // Epilogue. C/D layout: col = lane&15, row = quad*4+reg (m89/m91).
#pragma unroll
    for (int nt = 0; nt < 2; ++nt) {
        const int c = c0 + nt * 16 + lm;
        int v = x[c * kS + t];
        v = (v < 0) ? 0 : (v > kV - 1) ? (kV - 1) : v;
#pragma unroll
        for (int mt = 0; mt < 2; ++mt) {
            const int rb = r0 + mt * 16 + quad * 4;
            f32x4 cold = *(const f32x4*)(cT + (size_t)c * kH + rb);
            f32x4 cnew;
            s16x4 hnew;
#pragma unroll
            for (int reg = 0; reg < 4; ++reg) {
                const int r = rb + reg;
                float pg = clamp30(acc[0][mt][nt][reg] + Q[(0 * kH + r) * 4 + v]);
                float pi = clamp30(acc[1][mt][nt][reg] + Q[(1 * kH + r) * 4 + v]);
                float pf = clamp30(acc[2][mt][nt][reg] + Q[(2 * kH + r) * 4 + v]);
                float po = clamp30(acc[3][mt][nt][reg] + Q[(3 * kH + r) * 4 + v]);
                float gg = tanh_fast(pg);
                float ii = sigmoid_fast(pi);
                float ff = sigmoid_fast(pf);
                float oo = sigmoid_fast(po);
                float c2 = gg * ii + cold[reg] * ff;
                c2 = fminf(fmaxf(c2, -200.0f), 200.0f);   // legit |c| <= ~132
                cnew[reg] = c2;
                hnew[reg] = (short)f2b(tanh_fast(c2) * oo);
            }
            *(f32x4*)(cT + (size_t)c * kH + rb) = cnew;
            *(s16x4*)(hout + (size_t)c * kH + rb) = hnew;
        }
    }
}

// ---------------------------------------------------------------------------
// Logits: p[b][cls] = h[b,:] . W_ph[cls,:] + b_p[cls]; log_softmax over 10.
// One wave per batch row. Output fp32.
// ---------------------------------------------------------------------------
__global__ __launch_bounds__(256) void logits_kernel(
    const u16* __restrict__ hT, const float* __restrict__ Wph,
    const float* __restrict__ bp, float* __restrict__ out)
{
    const int wave = threadIdx.x >> 6;
    const int lane = threadIdx.x & 63;
    const int b = blockIdx.x * 4 + wave;

    const u16* hp = hT + (size_t)b * kH + lane * 16;
    float hf[16];
#pragma unroll
    for (int j = 0; j < 16; ++j) hf[j] = b2f(hp[j]);

    float p[kC];
#pragma unroll
    for (int cls = 0; cls < kC; ++cls) {
        const float* wp = Wph + (size_t)cls * kH + lane * 16;
        float s = 0.f;
#pragma unroll
        for (int j = 0; j < 16; ++j) s += hf[j] * wp[j];
#pragma unroll
        for (int off = 1; off < 64; off <<= 1) s += __shfl_xor(s, off, 64);
        p[cls] = fminf(fmaxf(s + bp[cls], -1.0e4f), 1.0e4f);  // drops NaN
    }

    float m = p[0];
#pragma unroll
    for (int cls = 1; cls < kC; ++cls) m = fmaxf(m, p[cls]);
    float se = 0.f;
#pragma unroll
    for (int cls = 0; cls < kC; ++cls) se += __expf(p[cls] - m);
    float l = m + __logf(se);

    if (lane < kC) {
        float myp = p[0];
#pragma unroll
        for (int cls = 1; cls < kC; ++cls)
            if (lane == cls) myp = p[cls];
        out[(size_t)b * kC + lane] = myp - l;
    }
}

// ---------------------------------------------------------------------------
extern "C" void kernel_launch(void* const* d_in, const int* in_sizes, int n_in,
                              void* d_out, int out_size, void* d_ws, size_t ws_size,
                              hipStream_t stream)
{
    const int*   x   = (const int*)  d_in[0];
    const float* emb = (const float*)d_in[1];
    const float* Wgx = (const float*)d_in[2];
    const float* Wgh = (const float*)d_in[3];
    const float* bg  = (const float*)d_in[4];
    const float* Wix = (const float*)d_in[5];
    const float* Wih = (const float*)d_in[6];
    const float* bi  = (const float*)d_in[7];
    const float* Wfx = (const float*)d_in[8];
    const float* Wfh = (const float*)d_in[9];
    const float* bf_ = (const float*)d_in[10];
    const float* Wox = (const float*)d_in[11];
    const float* Woh = (const float*)d_in[12];
    const float* bo  = (const float*)d_in[13];
    const float* Wph = (const float*)d_in[14];
    const float* bp  = (const float*)d_in[15];
    const float* h0  = (const float*)d_in[16];
    const float* c0  = (const float*)d_in[17];

    char* ws = (char*)d_ws;
    float* Q   = (float*)ws;                              // 64 KB
    u16*   hA  = (u16*)(ws + (64 << 10));                 // 2 MB
    u16*   hB  = hA + (size_t)kB * kH;                    // 2 MB
    float* cT  = (float*)(hB + (size_t)kB * kH);          // 4 MB
    u16*   wbf = (u16*)(cT + (size_t)kB * kH);            // 8 MB  (total ~16.1 MB)

    prep_weights<<<dim3(2048), dim3(256), 0, stream>>>(Wgh, Wih, Wfh, Woh, wbf);
    prep_hc<<<dim3(kB / 32, kH / 32), dim3(32, 32), 0, stream>>>(h0, c0, hA, cT);
    prep_q<<<dim3(16), dim3(256), 0, stream>>>(Wgx, Wix, Wfx, Wox, bg, bi, bf_, bo, emb, Q);

    for (int t = 0; t < kT; ++t) {
        const u16* hin  = (t & 1) ? hB : hA;
        u16*       hout = (t & 1) ? hA : hB;
        lstm_step<<<dim3(kB / 128, kH / 32), dim3(256), 0, stream>>>(
            (const short*)wbf, Q, x, t, (const short*)hin, hout, cT);
    }
    // 127 steps: t=126 (even) wrote hB.
    logits_kernel<<<dim3(kB / 4), dim3(256), 0, stream>>>(hB, Wph, bp, (float*)d_out);
}

// Round 7
// 3168.370 us; speedup vs baseline: 2.0841x; 2.0841x over previous
//
#include <hip/hip_runtime.h>

// LSTM: H=1024, B=1024, S=128 (T=127 steps), E=6, V=3, C=10.
// All float tensors FP32; x int32; output FP32 (1024 x 10).
// Multi-launch (known-good R6 skeleton). R7 changes: XCD-swizzled block
// mapping (weights L2-resident per XCD), LDS-staged weights via
// global_load_lds (kills 4x intra-block weight-read redundancy), frag-major
// pre-shuffled weight layout (conflict-free ds_read_b128), h b-frag prefetch.
constexpr int kH = 1024;
constexpr int kB = 1024;
constexpr int kS = 128;
constexpr int kT = 127;
constexpr int kE = 6;
constexpr int kV = 3;
constexpr int kC = 10;

typedef short s16x8 __attribute__((ext_vector_type(8)));
typedef short s16x4 __attribute__((ext_vector_type(4)));
typedef float f32x4 __attribute__((ext_vector_type(4)));
typedef unsigned short u16;

__device__ __forceinline__ float b2f(u16 u) {
    return __uint_as_float(((unsigned)u) << 16);
}
__device__ __forceinline__ u16 f2b(float f) {
    unsigned u = __float_as_uint(f);
    return (u16)((u + 0x7FFFu + ((u >> 16) & 1u)) >> 16);   // RNE
}
__device__ __forceinline__ float sigmoid_fast(float x) {
    return 1.0f / (1.0f + __expf(-x));
}
__device__ __forceinline__ float tanh_fast(float x) {
    return 2.0f / (1.0f + __expf(-2.0f * x)) - 1.0f;
}
__device__ __forceinline__ float clamp30(float x) {
    return fminf(fmaxf(x, -30.0f), 30.0f);
}

// async global->LDS, 16 B per lane (m97-verified width). LDS dest is
// wave-uniform base + lane*16; global side is a per-lane pointer.
__device__ __forceinline__ void async_copy16(const u16* g, u16* l) {
    __builtin_amdgcn_global_load_lds(
        (const __attribute__((address_space(1))) void*)g,
        (__attribute__((address_space(3))) void*)l, 16, 0, 0);
}

// ---------------------------------------------------------------------------
// Prep 1: weights fp32 -> bf16, shuffled into frag-major layout:
//   wsw[((((((by*8+kc)*4+g)*4+k0r)*2+mt)*4+quad)*16+lm)*8 + j]
//     = W_g[by*32 + mt*16 + lm][kc*128 + k0r*32 + quad*8 + j]
// so each block's chunk (by,kc) is a contiguous 32 KB whose LDS image gives
// lane-contiguous ds_read_b128 fragments. 2048 blocks x 256 thr x 8 elems.
// ---------------------------------------------------------------------------
__global__ __launch_bounds__(256) void prep_weights(
    const float* __restrict__ Wgh, const float* __restrict__ Wih,
    const float* __restrict__ Wfh, const float* __restrict__ Woh,
    u16* __restrict__ wsw)
{
    unsigned grp = blockIdx.x * 256 + threadIdx.x;    // 0 .. 2^19-1
    const int lm   = grp & 15;
    const int quad = (grp >> 4) & 3;
    const int mt   = (grp >> 6) & 1;
    const int k0r  = (grp >> 7) & 3;
    const int g    = (grp >> 9) & 3;
    const int kc   = (grp >> 11) & 7;
    const int by   = grp >> 14;
    const float* src = (g == 0) ? Wgh : (g == 1) ? Wih : (g == 2) ? Wfh : Woh;
    const int row = by * 32 + mt * 16 + lm;
    const int k   = kc * 128 + k0r * 32 + quad * 8;
    f32x4 v0 = *(const f32x4*)(src + (size_t)row * kH + k);
    f32x4 v1 = *(const f32x4*)(src + (size_t)row * kH + k + 4);
    s16x8 o;
#pragma unroll
    for (int j = 0; j < 4; ++j) o[j] = (short)f2b(v0[j]);
#pragma unroll
    for (int j = 0; j < 4; ++j) o[4 + j] = (short)f2b(v1[j]);
    *(s16x8*)(wsw + (size_t)grp * 8) = o;
}

// ---------------------------------------------------------------------------
// Prep 2: transpose h0 (H,B) fp32 -> hA (B,H) bf16; c0 (H,B) -> cT (B,H) fp32.
// ---------------------------------------------------------------------------
__global__ __launch_bounds__(1024) void prep_hc(
    const float* __restrict__ h0, const float* __restrict__ c0,
    u16* __restrict__ hA, float* __restrict__ cT)
{
    __shared__ float th[32][33];
    __shared__ float tc[32][33];
    int b = blockIdx.x * 32 + threadIdx.x;
    int h = blockIdx.y * 32 + threadIdx.y;
    th[threadIdx.y][threadIdx.x] = h0[(size_t)h * kB + b];
    tc[threadIdx.y][threadIdx.x] = c0[(size_t)h * kB + b];
    __syncthreads();
    int ob = blockIdx.x * 32 + threadIdx.y;
    int oh = blockIdx.y * 32 + threadIdx.x;
    hA[(size_t)ob * kH + oh] = f2b(th[threadIdx.x][threadIdx.y]);
    cT[(size_t)ob * kH + oh] = tc[threadIdx.x][threadIdx.y];
}

// ---------------------------------------------------------------------------
// Prep 3: Q[g][h][v] = b_g[h] + sum_e W_gx[h,e]*emb[v,e]  (fp32, stride 4)
// ---------------------------------------------------------------------------
__global__ __launch_bounds__(256) void prep_q(
    const float* __restrict__ Wgx, const float* __restrict__ Wix,
    const float* __restrict__ Wfx, const float* __restrict__ Wox,
    const float* __restrict__ bg,  const float* __restrict__ bi,
    const float* __restrict__ bf_, const float* __restrict__ bo,
    const float* __restrict__ emb, float* __restrict__ Q)
{
    int tid = blockIdx.x * blockDim.x + threadIdx.x;
    if (tid >= 4 * kH) return;
    int g = tid >> 10;
    int h = tid & (kH - 1);
    const float* Wx = (g == 0) ? Wgx : (g == 1) ? Wix : (g == 2) ? Wfx : Wox;
    const float* bb = (g == 0) ? bg  : (g == 1) ? bi  : (g == 2) ? bf_ : bo;
    float w[kE];
#pragma unroll
    for (int e = 0; e < kE; ++e) w[e] = Wx[h * kE + e];
#pragma unroll
    for (int v = 0; v < kV; ++v) {
        float s = bb[h];
#pragma unroll
        for (int e = 0; e < kE; ++e) s += w[e] * emb[v * kE + e];
        Q[tid * 4 + v] = s;
    }
    Q[tid * 4 + 3] = 0.0f;
}

// ---------------------------------------------------------------------------
// One LSTM timestep. 1D grid 256 blocks, 256 thr (4 waves).
// XCD swizzle: xcd=blk&7, slot=blk>>3, by=xcd*4+(slot&3), bx=slot>>2
//   -> per-XCD L2 working set: 1 MB weights + 2 MB h + 0.5 MB c (fits 4 MB).
// Weights: K-chunked (8 x 128) LDS double-buffer via global_load_lds(16B).
// Wave w: all 4 gates x 32 rows x cols [bx*128+32w,+32). h direct from global.
// ---------------------------------------------------------------------------
__global__ __launch_bounds__(256) void lstm_step(
    const u16* __restrict__ wsw, const float* __restrict__ Q,
    const int* __restrict__ x, int t,
    const short* __restrict__ hin, u16* __restrict__ hout,
    float* __restrict__ cT)
{
    __shared__ u16 wlds[2][16384];   // 2 x 32 KB

    const int tid  = threadIdx.x;
    const int lane = tid & 63;
    const int wave = tid >> 6;
    const int lm   = lane & 15;
    const int quad = lane >> 4;
    const int blk  = blockIdx.x;
    const int xcd  = blk & 7;
    const int slot = blk >> 3;
    const int by   = xcd * 4 + (slot & 3);
    const int bx   = slot >> 2;
    const int r0 = by * 32;
    const int c0 = bx * 128 + wave * 32;

    const u16* wswblk = wsw + (size_t)by * 8 * 16384;   // this block's 8 chunks

    f32x4 acc[4][2][2];
    const f32x4 zero = {0.f, 0.f, 0.f, 0.f};
#pragma unroll
    for (int g = 0; g < 4; ++g)
#pragma unroll
        for (int m = 0; m < 2; ++m)
#pragma unroll
            for (int n = 0; n < 2; ++n) acc[g][m][n] = zero;

    const int koff = quad * 8;
    const short* hrow0 = hin + (size_t)(c0 + lm) * kH + koff;
    const short* hrow1 = hin + (size_t)(c0 + 16 + lm) * kH + koff;

    // Stage chunk 0 into buf 0 (each wave stages 8 KB = 8 x 1 KB).
    {
        const u16* gsrc = wswblk;
#pragma unroll
        for (int rr = 0; rr < 8; ++rr) {
            const int ubase = wave * 512 + rr * 64;
            async_copy16(gsrc + (size_t)(ubase + lane) * 8, &wlds[0][ubase * 8]);
        }
        asm volatile("s_waitcnt vmcnt(0)" ::: "memory");
        __syncthreads();
    }

    // b-frag prefetch registers (k=0)
    s16x8 b0c = *(const s16x8*)(hrow0);
    s16x8 b1c = *(const s16x8*)(hrow1);

#pragma unroll 1
    for (int kc = 0; kc < 8; ++kc) {
        const int cur = kc & 1;
        if (kc < 7) {   // stage next chunk into other buffer (async)
            const u16* gsrc = wswblk + (size_t)(kc + 1) * 16384;
#pragma unroll
            for (int rr = 0; rr < 8; ++rr) {
                const int ubase = wave * 512 + rr * 64;
                async_copy16(gsrc + (size_t)(ubase + lane) * 8,
                             &wlds[cur ^ 1][ubase * 8]);
            }
        }
#pragma unroll
        for (int k0r = 0; k0r < 4; ++k0r) {
            s16x8 b0n = {0,0,0,0,0,0,0,0}, b1n = {0,0,0,0,0,0,0,0};
            const int nk = kc * 128 + (k0r + 1) * 32;   // next k (uniform)
            if (nk < kH) {
                b0n = *(const s16x8*)(hrow0 + nk);
                b1n = *(const s16x8*)(hrow1 + nk);
            }
#pragma unroll
            for (int g = 0; g < 4; ++g) {
                const int f0 = ((g * 4 + k0r) * 2 + 0) * 64 + lane;
                const int f1 = ((g * 4 + k0r) * 2 + 1) * 64 + lane;
                s16x8 a0 = *(const s16x8*)&wlds[cur][f0 * 8];
                s16x8 a1 = *(const s16x8*)&wlds[cur][f1 * 8];
                acc[g][0][0] = __builtin_amdgcn_mfma_f32_16x16x32_bf16(a0, b0c, acc[g][0][0], 0, 0, 0);
                acc[g][0][1] = __builtin_amdgcn_mfma_f32_16x16x32_bf16(a0, b1c, acc[g][0][1], 0, 0, 0);
                acc[g][1][0] = __builtin_amdgcn_mfma_f32_16x16x32_bf16(a1, b0c, acc[g][1][0], 0, 0, 0);
                acc[g][1][1] = __builtin_amdgcn_mfma_f32_16x16x32_bf16(a1, b1c, acc[g][1][1], 0, 0, 0);
            }
            b0c = b0n;
            b1c = b1n;
        }
        if (kc < 7) {   // staging of next buf complete before it is consumed
            asm volatile("s_waitcnt vmcnt(0)" ::: "memory");
            __syncthreads();
        }
    }

    // Epilogue. C/D layout: col = lane&15, row = quad*4+reg (m89/m91).
#pragma unroll
    for (int nt = 0; nt < 2; ++nt) {
        const int c = c0 + nt * 16 + lm;
        int v = x[c * kS + t];
        v = (v < 0) ? 0 : (v > kV - 1) ? (kV - 1) : v;
#pragma unroll
        for (int mt = 0; mt < 2; ++mt) {
            const int rb = r0 + mt * 16 + quad * 4;
            f32x4 cold = *(const f32x4*)(cT + (size_t)c * kH + rb);
            f32x4 cnew;
            s16x4 hnew;
#pragma unroll
            for (int reg = 0; reg < 4; ++reg) {
                const int r = rb + reg;
                float pg = clamp30(acc[0][mt][nt][reg] + Q[(0 * kH + r) * 4 + v]);
                float pi = clamp30(acc[1][mt][nt][reg] + Q[(1 * kH + r) * 4 + v]);
                float pf = clamp30(acc[2][mt][nt][reg] + Q[(2 * kH + r) * 4 + v]);
                float po = clamp30(acc[3][mt][nt][reg] + Q[(3 * kH + r) * 4 + v]);
                float gg = tanh_fast(pg);
                float ii = sigmoid_fast(pi);
                float ff = sigmoid_fast(pf);
                float oo = sigmoid_fast(po);
                float c2 = gg * ii + cold[reg] * ff;
                c2 = fminf(fmaxf(c2, -200.0f), 200.0f);
                cnew[reg] = c2;
                hnew[reg] = (short)f2b(tanh_fast(c2) * oo);
            }
            *(f32x4*)(cT + (size_t)c * kH + rb) = cnew;
            *(s16x4*)(hout + (size_t)c * kH + rb) = hnew;
        }
    }
}

// ---------------------------------------------------------------------------
// Logits: p[b][cls] = h[b,:] . W_ph[cls,:] + b_p[cls]; log_softmax over 10.
// ---------------------------------------------------------------------------
__global__ __launch_bounds__(256) void logits_kernel(
    const u16* __restrict__ hT, const float* __restrict__ Wph,
    const float* __restrict__ bp, float* __restrict__ out)
{
    const int wave = threadIdx.x >> 6;
    const int lane = threadIdx.x & 63;
    const int b = blockIdx.x * 4 + wave;

    const u16* hp = hT + (size_t)b * kH + lane * 16;
    float hf[16];
#pragma unroll
    for (int j = 0; j < 16; ++j) hf[j] = b2f(hp[j]);

    float p[kC];
#pragma unroll
    for (int cls = 0; cls < kC; ++cls) {
        const float* wp = Wph + (size_t)cls * kH + lane * 16;
        float s = 0.f;
#pragma unroll
        for (int j = 0; j < 16; ++j) s += hf[j] * wp[j];
#pragma unroll
        for (int off = 1; off < 64; off <<= 1) s += __shfl_xor(s, off, 64);
        p[cls] = fminf(fmaxf(s + bp[cls], -1.0e4f), 1.0e4f);
    }

    float m = p[0];
#pragma unroll
    for (int cls = 1; cls < kC; ++cls) m = fmaxf(m, p[cls]);
    float se = 0.f;
#pragma unroll
    for (int cls = 0; cls < kC; ++cls) se += __expf(p[cls] - m);
    float l = m + __logf(se);

    if (lane < kC) {
        float myp = p[0];
#pragma unroll
        for (int cls = 1; cls < kC; ++cls)
            if (lane == cls) myp = p[cls];
        out[(size_t)b * kC + lane] = myp - l;
    }
}

// ---------------------------------------------------------------------------
extern "C" void kernel_launch(void* const* d_in, const int* in_sizes, int n_in,
                              void* d_out, int out_size, void* d_ws, size_t ws_size,
                              hipStream_t stream)
{
    const int*   x   = (const int*)  d_in[0];
    const float* emb = (const float*)d_in[1];
    const float* Wgx = (const float*)d_in[2];
    const float* Wgh = (const float*)d_in[3];
    const float* bg  = (const float*)d_in[4];
    const float* Wix = (const float*)d_in[5];
    const float* Wih = (const float*)d_in[6];
    const float* bi  = (const float*)d_in[7];
    const float* Wfx = (const float*)d_in[8];
    const float* Wfh = (const float*)d_in[9];
    const float* bf_ = (const float*)d_in[10];
    const float* Wox = (const float*)d_in[11];
    const float* Woh = (const float*)d_in[12];
    const float* bo  = (const float*)d_in[13];
    const float* Wph = (const float*)d_in[14];
    const float* bp  = (const float*)d_in[15];
    const float* h0  = (const float*)d_in[16];
    const float* c0  = (const float*)d_in[17];

    char* ws = (char*)d_ws;
    float* Q   = (float*)ws;                              // 64 KB
    u16*   hA  = (u16*)(ws + (64 << 10));                 // 2 MB
    u16*   hB  = hA + (size_t)kB * kH;                    // 2 MB
    float* cT  = (float*)(hB + (size_t)kB * kH);          // 4 MB
    u16*   wsw = (u16*)(cT + (size_t)kB * kH);            // 8 MB  (total ~16.1 MB)

    prep_weights<<<dim3(2048), dim3(256), 0, stream>>>(Wgh, Wih, Wfh, Woh, wsw);
    prep_hc<<<dim3(kB / 32, kH / 32), dim3(32, 32), 0, stream>>>(h0, c0, hA, cT);
    prep_q<<<dim3(16), dim3(256), 0, stream>>>(Wgx, Wix, Wfx, Wox, bg, bi, bf_, bo, emb, Q);

    for (int t = 0; t < kT; ++t) {
        const u16* hin  = (t & 1) ? hB : hA;
        u16*       hout = (t & 1) ? hA : hB;
        lstm_step<<<dim3(256), dim3(256), 0, stream>>>(
            wsw, Q, x, t, (const short*)hin, hout, cT);
    }
    // 127 steps: t=126 (even) wrote hB.
    logits_kernel<<<dim3(kB / 4), dim3(256), 0, stream>>>(hB, Wph, bp, (float*)d_out);
}

// Round 8
// 2936.017 us; speedup vs baseline: 2.2491x; 1.0791x over previous
//
#include <hip/hip_runtime.h>

// LSTM: H=1024, B=1024, S=128 (T=127 steps), E=6, V=3, C=10.
// All float tensors FP32; x int32; output FP32 (1024 x 10).
// R8: occupancy fix. 512 blocks (2/CU -> 2 waves/SIMD), 16-row x 4-gate x
// 128-col tiles, 4 K-chunks of 256 (32 KB LDS chunks, 64 KB double-buffer,
// 4 barriers/step instead of 8). Weights pre-shuffled frag-major; staged via
// global_load_lds(16B). XCD swizzle keeps 1 MB weights L2-resident per XCD.
constexpr int kH = 1024;
constexpr int kB = 1024;
constexpr int kS = 128;
constexpr int kT = 127;
constexpr int kE = 6;
constexpr int kV = 3;
constexpr int kC = 10;

typedef short s16x8 __attribute__((ext_vector_type(8)));
typedef short s16x4 __attribute__((ext_vector_type(4)));
typedef float f32x4 __attribute__((ext_vector_type(4)));
typedef unsigned short u16;

__device__ __forceinline__ float b2f(u16 u) {
    return __uint_as_float(((unsigned)u) << 16);
}
__device__ __forceinline__ u16 f2b(float f) {
    unsigned u = __float_as_uint(f);
    return (u16)((u + 0x7FFFu + ((u >> 16) & 1u)) >> 16);   // RNE
}
__device__ __forceinline__ float sigmoid_fast(float x) {
    return 1.0f / (1.0f + __expf(-x));
}
__device__ __forceinline__ float tanh_fast(float x) {
    return 2.0f / (1.0f + __expf(-2.0f * x)) - 1.0f;
}
__device__ __forceinline__ float clamp30(float x) {
    return fminf(fmaxf(x, -30.0f), 30.0f);
}

__device__ __forceinline__ void async_copy16(const u16* g, u16* l) {
    __builtin_amdgcn_global_load_lds(
        (const __attribute__((address_space(1))) void*)g,
        (__attribute__((address_space(3))) void*)l, 16, 0, 0);
}

// ---------------------------------------------------------------------------
// Prep 1: weights fp32 -> bf16, frag-major for 16-row tiles:
//   grp = (((by*4 + kc)*4 + g)*8 + k0)*64 + lane ; lane = quad*16 + lm
//   wsw[grp*8 + j] = W_g[by*16 + lm][kc*256 + k0*32 + quad*8 + j]
// Each (by,kc) chunk = 16384 shorts = 32 KB contiguous; its LDS image gives
// lane-contiguous ds_read_b128 a-fragments. 2048 blocks x 256 thr x 8 elems.
// ---------------------------------------------------------------------------
__global__ __launch_bounds__(256) void prep_weights(
    const float* __restrict__ Wgh, const float* __restrict__ Wih,
    const float* __restrict__ Wfh, const float* __restrict__ Woh,
    u16* __restrict__ wsw)
{
    unsigned grp = blockIdx.x * 256 + threadIdx.x;    // 0 .. 2^19-1
    const int lane = grp & 63;
    const int lm   = lane & 15;
    const int quad = lane >> 4;
    const int k0   = (grp >> 6) & 7;
    const int g    = (grp >> 9) & 3;
    const int kc   = (grp >> 11) & 3;
    const int by   = grp >> 13;                       // 0..63
    const float* src = (g == 0) ? Wgh : (g == 1) ? Wih : (g == 2) ? Wfh : Woh;
    const int row = by * 16 + lm;
    const int k   = kc * 256 + k0 * 32 + quad * 8;
    f32x4 v0 = *(const f32x4*)(src + (size_t)row * kH + k);
    f32x4 v1 = *(const f32x4*)(src + (size_t)row * kH + k + 4);
    s16x8 o;
#pragma unroll
    for (int j = 0; j < 4; ++j) o[j] = (short)f2b(v0[j]);
#pragma unroll
    for (int j = 0; j < 4; ++j) o[4 + j] = (short)f2b(v1[j]);
    *(s16x8*)(wsw + (size_t)grp * 8) = o;
}

// ---------------------------------------------------------------------------
// Prep 2: transpose h0 (H,B) fp32 -> hA (B,H) bf16; c0 (H,B) -> cT (B,H) fp32.
// ---------------------------------------------------------------------------
__global__ __launch_bounds__(1024) void prep_hc(
    const float* __restrict__ h0, const float* __restrict__ c0,
    u16* __restrict__ hA, float* __restrict__ cT)
{
    __shared__ float th[32][33];
    __shared__ float tc[32][33];
    int b = blockIdx.x * 32 + threadIdx.x;
    int h = blockIdx.y * 32 + threadIdx.y;
    th[threadIdx.y][threadIdx.x] = h0[(size_t)h * kB + b];
    tc[threadIdx.y][threadIdx.x] = c0[(size_t)h * kB + b];
    __syncthreads();
    int ob = blockIdx.x * 32 + threadIdx.y;
    int oh = blockIdx.y * 32 + threadIdx.x;
    hA[(size_t)ob * kH + oh] = f2b(th[threadIdx.x][threadIdx.y]);
    cT[(size_t)ob * kH + oh] = tc[threadIdx.x][threadIdx.y];
}

// ---------------------------------------------------------------------------
// Prep 3: Q[g][h][v] = b_g[h] + sum_e W_gx[h,e]*emb[v,e]  (fp32, stride 4)
// ---------------------------------------------------------------------------
__global__ __launch_bounds__(256) void prep_q(
    const float* __restrict__ Wgx, const float* __restrict__ Wix,
    const float* __restrict__ Wfx, const float* __restrict__ Wox,
    const float* __restrict__ bg,  const float* __restrict__ bi,
    const float* __restrict__ bf_, const float* __restrict__ bo,
    const float* __restrict__ emb, float* __restrict__ Q)
{
    int tid = blockIdx.x * blockDim.x + threadIdx.x;
    if (tid >= 4 * kH) return;
    int g = tid >> 10;
    int h = tid & (kH - 1);
    const float* Wx = (g == 0) ? Wgx : (g == 1) ? Wix : (g == 2) ? Wfx : Wox;
    const float* bb = (g == 0) ? bg  : (g == 1) ? bi  : (g == 2) ? bf_ : bo;
    float w[kE];
#pragma unroll
    for (int e = 0; e < kE; ++e) w[e] = Wx[h * kE + e];
#pragma unroll
    for (int v = 0; v < kV; ++v) {
        float s = bb[h];
#pragma unroll
        for (int e = 0; e < kE; ++e) s += w[e] * emb[v * kE + e];
        Q[tid * 4 + v] = s;
    }
    Q[tid * 4 + 3] = 0.0f;
}

// ---------------------------------------------------------------------------
// One LSTM timestep. Grid 512 x 256 thr (4 waves) -> 2 blocks/CU, 2 waves/SIMD.
// Block tile: 16 h-rows x 4 gates x 128 cols. Wave w: cols [bx*128+32w,+32).
// XCD swizzle: xcd=blk&7, slot=blk>>3, by=xcd*8+(slot&7), bx=slot>>3.
// Weights: 4 K-chunks of 256, 32 KB each, LDS double-buffer (64 KB).
// ---------------------------------------------------------------------------
__global__ __launch_bounds__(256, 2) void lstm_step(
    const u16* __restrict__ wsw, const float* __restrict__ Q,
    const int* __restrict__ x, int t,
    const short* __restrict__ hin, u16* __restrict__ hout,
    float* __restrict__ cT)
{
    __shared__ u16 wlds[2][16384];   // 2 x 32 KB

    const int tid  = threadIdx.x;
    const int lane = tid & 63;
    const int wave = tid >> 6;
    const int lm   = lane & 15;
    const int quad = lane >> 4;
    const int blk  = blockIdx.x;
    const int xcd  = blk & 7;
    const int slot = blk >> 3;            // 0..63
    const int by   = xcd * 8 + (slot & 7);  // 0..63
    const int bx   = slot >> 3;             // 0..7
    const int r0 = by * 16;
    const int c0 = bx * 128 + wave * 32;

    const u16* wswblk = wsw + (size_t)by * 65536;   // 4 chunks x 16384 shorts

    f32x4 acc[4][2];
    const f32x4 zero = {0.f, 0.f, 0.f, 0.f};
#pragma unroll
    for (int g = 0; g < 4; ++g)
#pragma unroll
        for (int n = 0; n < 2; ++n) acc[g][n] = zero;

    const int koff = quad * 8;
    const short* hrow0 = hin + (size_t)(c0 + lm) * kH + koff;
    const short* hrow1 = hin + (size_t)(c0 + 16 + lm) * kH + koff;

    // Stage chunk 0 into buf 0: 32 KB / block; per wave 8 KB = 8 x 1 KB.
    {
        const u16* gsrc = wswblk;
#pragma unroll
        for (int rr = 0; rr < 8; ++rr) {
            const int ub = wave * 4096 + rr * 512;   // shorts
            async_copy16(gsrc + ub + lane * 8, &wlds[0][ub]);
        }
        asm volatile("s_waitcnt vmcnt(0)" ::: "memory");
        __syncthreads();
    }

    // b-frag prefetch (k=0)
    s16x8 b0c = *(const s16x8*)(hrow0);
    s16x8 b1c = *(const s16x8*)(hrow1);

#pragma unroll 1
    for (int kc = 0; kc < 4; ++kc) {
        const int cur = kc & 1;
        if (kc < 3) {   // stage next chunk into other buffer (async)
            const u16* gsrc = wswblk + (size_t)(kc + 1) * 16384;
#pragma unroll
            for (int rr = 0; rr < 8; ++rr) {
                const int ub = wave * 4096 + rr * 512;
                async_copy16(gsrc + ub + lane * 8, &wlds[cur ^ 1][ub]);
            }
        }
#pragma unroll
        for (int k0 = 0; k0 < 8; ++k0) {
            s16x8 b0n = {0,0,0,0,0,0,0,0}, b1n = {0,0,0,0,0,0,0,0};
            const int nk = kc * 256 + (k0 + 1) * 32;   // next k (uniform)
            if (nk < kH) {
                b0n = *(const s16x8*)(hrow0 + nk);
                b1n = *(const s16x8*)(hrow1 + nk);
            }
#pragma unroll
            for (int g = 0; g < 4; ++g) {
                const int f = ((g * 8 + k0) * 64 + lane) * 8;   // shorts
                s16x8 a = *(const s16x8*)&wlds[cur][f];
                acc[g][0] = __builtin_amdgcn_mfma_f32_16x16x32_bf16(a, b0c, acc[g][0], 0, 0, 0);
                acc[g][1] = __builtin_amdgcn_mfma_f32_16x16x32_bf16(a, b1c, acc[g][1], 0, 0, 0);
            }
            b0c = b0n;
            b1c = b1n;
        }
        if (kc < 3) {
            asm volatile("s_waitcnt vmcnt(0)" ::: "memory");
            __syncthreads();
        }
    }

    // Epilogue. C/D layout: col = lane&15, row = quad*4+reg (m89/m91).
#pragma unroll
    for (int nt = 0; nt < 2; ++nt) {
        const int c = c0 + nt * 16 + lm;
        int v = x[c * kS + t];
        v = (v < 0) ? 0 : (v > kV - 1) ? (kV - 1) : v;
        const int rb = r0 + quad * 4;
        f32x4 cold = *(const f32x4*)(cT + (size_t)c * kH + rb);
        f32x4 cnew;
        s16x4 hnew;
#pragma unroll
        for (int reg = 0; reg < 4; ++reg) {
            const int r = rb + reg;
            float pg = clamp30(acc[0][nt][reg] + Q[(0 * kH + r) * 4 + v]);
            float pi = clamp30(acc[1][nt][reg] + Q[(1 * kH + r) * 4 + v]);
            float pf = clamp30(acc[2][nt][reg] + Q[(2 * kH + r) * 4 + v]);
            float po = clamp30(acc[3][nt][reg] + Q[(3 * kH + r) * 4 + v]);
            float gg = tanh_fast(pg);
            float ii = sigmoid_fast(pi);
            float ff = sigmoid_fast(pf);
            float oo = sigmoid_fast(po);
            float c2 = gg * ii + cold[reg] * ff;
            c2 = fminf(fmaxf(c2, -200.0f), 200.0f);
            cnew[reg] = c2;
            hnew[reg] = (short)f2b(tanh_fast(c2) * oo);
        }
        *(f32x4*)(cT + (size_t)c * kH + rb) = cnew;
        *(s16x4*)(hout + (size_t)c * kH + rb) = hnew;
    }
}

// ---------------------------------------------------------------------------
// Logits: p[b][cls] = h[b,:] . W_ph[cls,:] + b_p[cls]; log_softmax over 10.
// ---------------------------------------------------------------------------
__global__ __launch_bounds__(256) void logits_kernel(
    const u16* __restrict__ hT, const float* __restrict__ Wph,
    const float* __restrict__ bp, float* __restrict__ out)
{
    const int wave = threadIdx.x >> 6;
    const int lane = threadIdx.x & 63;
    const int b = blockIdx.x * 4 + wave;

    const u16* hp = hT + (size_t)b * kH + lane * 16;
    float hf[16];
#pragma unroll
    for (int j = 0; j < 16; ++j) hf[j] = b2f(hp[j]);

    float p[kC];
#pragma unroll
    for (int cls = 0; cls < kC; ++cls) {
        const float* wp = Wph + (size_t)cls * kH + lane * 16;
        float s = 0.f;
#pragma unroll
        for (int j = 0; j < 16; ++j) s += hf[j] * wp[j];
#pragma unroll
        for (int off = 1; off < 64; off <<= 1) s += __shfl_xor(s, off, 64);
        p[cls] = fminf(fmaxf(s + bp[cls], -1.0e4f), 1.0e4f);
    }

    float m = p[0];
#pragma unroll
    for (int cls = 1; cls < kC; ++cls) m = fmaxf(m, p[cls]);
    float se = 0.f;
#pragma unroll
    for (int cls = 0; cls < kC; ++cls) se += __expf(p[cls] - m);
    float l = m + __logf(se);

    if (lane < kC) {
        float myp = p[0];
#pragma unroll
        for (int cls = 1; cls < kC; ++cls)
            if (lane == cls) myp = p[cls];
        out[(size_t)b * kC + lane] = myp - l;
    }
}

// ---------------------------------------------------------------------------
extern "C" void kernel_launch(void* const* d_in, const int* in_sizes, int n_in,
                              void* d_out, int out_size, void* d_ws, size_t ws_size,
                              hipStream_t stream)
{
    const int*   x   = (const int*)  d_in[0];
    const float* emb = (const float*)d_in[1];
    const float* Wgx = (const float*)d_in[2];
    const float* Wgh = (const float*)d_in[3];
    const float* bg  = (const float*)d_in[4];
    const float* Wix = (const float*)d_in[5];
    const float* Wih = (const float*)d_in[6];
    const float* bi  = (const float*)d_in[7];
    const float* Wfx = (const float*)d_in[8];
    const float* Wfh = (const float*)d_in[9];
    const float* bf_ = (const float*)d_in[10];
    const float* Wox = (const float*)d_in[11];
    const float* Woh = (const float*)d_in[12];
    const float* bo  = (const float*)d_in[13];
    const float* Wph = (const float*)d_in[14];
    const float* bp  = (const float*)d_in[15];
    const float* h0  = (const float*)d_in[16];
    const float* c0  = (const float*)d_in[17];

    char* ws = (char*)d_ws;
    float* Q   = (float*)ws;                              // 64 KB
    u16*   hA  = (u16*)(ws + (64 << 10));                 // 2 MB
    u16*   hB  = hA + (size_t)kB * kH;                    // 2 MB
    float* cT  = (float*)(hB + (size_t)kB * kH);          // 4 MB
    u16*   wsw = (u16*)(cT + (size_t)kB * kH);            // 8 MB  (total ~16.1 MB)

    prep_weights<<<dim3(2048), dim3(256), 0, stream>>>(Wgh, Wih, Wfh, Woh, wsw);
    prep_hc<<<dim3(kB / 32, kH / 32), dim3(32, 32), 0, stream>>>(h0, c0, hA, cT);
    prep_q<<<dim3(16), dim3(256), 0, stream>>>(Wgx, Wix, Wfx, Wox, bg, bi, bf_, bo, emb, Q);

    for (int t = 0; t < kT; ++t) {
        const u16* hin  = (t & 1) ? hB : hA;
        u16*       hout = (t & 1) ? hA : hB;
        lstm_step<<<dim3(512), dim3(256), 0, stream>>>(
            wsw, Q, x, t, (const short*)hin, hout, cT);
    }
    // 127 steps: t=126 (even) wrote hB.
    logits_kernel<<<dim3(kB / 4), dim3(256), 0, stream>>>(hB, Wph, bp, (float*)d_out);
}